// Round 5
// baseline (707.795 us; speedup 1.0000x reference)
//
#include <hip/hip_runtime.h>

typedef __attribute__((ext_vector_type(8))) short short8;
typedef __attribute__((ext_vector_type(4))) float f32x4;

__device__ __forceinline__ unsigned short f2b(float f) {
  unsigned int u = __builtin_bit_cast(unsigned int, f);
  u += 0x7fffu + ((u >> 16) & 1u);   // RNE; inputs are finite
  return (unsigned short)(u >> 16);
}
__device__ __forceinline__ float b2f(unsigned short s) {
  unsigned int u = ((unsigned int)s) << 16;
  return __builtin_bit_cast(float, u);
}

// ---------- pack A (activations) f32 row-major [N][K] -> flat MFMA frag blocks ----------
// frag F = R*(K/32) + S  (R = 16-row block, S = 32-k step), 1KB each:
// lane l bytes [l*16, l*16+16) = bf16 A[R*16 + (l&15)][S*32 + (l>>4)*8 + 0..7]
__global__ __launch_bounds__(256) void pack_a_k(const float* __restrict__ in,
                                                unsigned short* __restrict__ out, int K) {
  int R = blockIdx.x, t = threadIdx.x;
  int NS = K / 32;
  for (int i = 0; i < K / 128; ++i) {
    int c = t + 256 * i;            // chunk id: S = c>>6, lane = c&63
    int S = c >> 6, l = c & 63;
    int row = R * 16 + (l & 15);
    int k = S * 32 + (l >> 4) * 8;
    const float4* p = (const float4*)(in + (size_t)row * K + k);
    float4 a = p[0], b = p[1];
    short8 v;
    v[0] = (short)f2b(a.x); v[1] = (short)f2b(a.y);
    v[2] = (short)f2b(a.z); v[3] = (short)f2b(a.w);
    v[4] = (short)f2b(b.x); v[5] = (short)f2b(b.y);
    v[6] = (short)f2b(b.z); v[7] = (short)f2b(b.w);
    ((short8*)out)[(size_t)(R * NS + S) * 64 + l] = v;
  }
}

// ---------- pack B (weights) f32 [K][C] -> flat frag blocks over output-cols ----------
// INTER=1 (Wv): output col index p = 4*(c&1023) + (c>>10) (head interleave), so
// source col for p is c = (p&3)*1024 + (p>>2).  frag F = P*(K/32) + S, P = 16-col block.
// lane l bytes = bf16 B[col = P*16 + (l&15)][k = S*32 + (l>>4)*8 + 0..7]
template <int INTER>
__global__ __launch_bounds__(256) void pack_b_k(const float* __restrict__ in,
                                                unsigned short* __restrict__ out,
                                                int K, int C) {
  __shared__ float tl[128][17];
  int P = blockIdx.x, kc = blockIdx.y, t = threadIdx.x;
  int k0 = kc * 128;
  // stage 128 k-rows x 16 cols. cols come in 4 groups of 4 consecutive source cols.
#pragma unroll
  for (int ii = 0; ii < 2; ++ii) {
    int id = t + 256 * ii;          // 512 float4 loads
    int k = id >> 2, g = id & 3;
    int cbase;
    if (INTER) cbase = g * 1024 + P * 4;      // group g = h; pi(q) = q*4+g
    else       cbase = P * 16 + g * 4;        // pi(q) = g*4+q
    float4 f = *(const float4*)(in + (size_t)(k0 + k) * C + cbase);
#pragma unroll
    for (int q = 0; q < 4; ++q) {
      int pi = INTER ? (q * 4 + g) : (g * 4 + q);
      tl[k][pi] = ((const float*)&f)[q];
    }
  }
  __syncthreads();
  // emit 4 S-frags (128 k = 4 K-steps), 64 lane-chunks each -> 256 chunks, 1/thread
  int Sl = t >> 6, l = t & 63;
  short8 v;
#pragma unroll
  for (int j = 0; j < 8; ++j)
    v[j] = (short)f2b(tl[Sl * 32 + (l >> 4) * 8 + j][l & 15]);
  int NS = K / 32;
  ((short8*)out)[(size_t)(P * NS + kc * 4 + Sl) * 64 + l] = v;
}

// ---------- unified flat GEMM: no LDS staging, no barriers in K-loop ----------
// Block 256(M) x 128(N), 8 waves (4m x 2n), wave tile 64x64, acc[4][4] (64 regs).
// Operands stream global->reg (dwordx4, saddr) with 1-step register double buffer;
// compiler derives counted vmcnt (AITER flatmm pattern).
// EPI 0: Qb bf16 = acc + bias[col]
// EPI 1: sc[row][nt] = sum_col (acc+bias[col]) * Qb[row][col]   (one head per block)
// EPI 2: Z[row][d] = max_h sc[row][h]*(acc+bv), cols head-interleaved p=4d+h
template <int KD, int NTI, int EPI>
__global__ __launch_bounds__(512, 3) void gemm_flat(
    const unsigned short* __restrict__ Af, const unsigned short* __restrict__ Bf,
    const float* __restrict__ bias, const unsigned short* __restrict__ Qb,
    unsigned short* __restrict__ outb, float* __restrict__ sc,
    float* __restrict__ Z) {
  constexpr int NS = KD / 32;
  constexpr int SMB = (EPI == 2) ? (36864) : 2048;
  __shared__ __align__(16) char smem[SMB];

  int tid = threadIdx.x;
  int bid = blockIdx.x;
  int cpx = gridDim.x >> 3;                  // grid % 8 == 0 (bijective XCD swizzle)
  int lb = (bid & 7) * cpx + (bid >> 3);
  int mtile = lb / NTI, nt = lb % NTI;
  long m0 = (long)mtile * 256;
  int l = tid & 63, wid = tid >> 6, wm = wid >> 1, wn = wid & 1;

  float* s_sc = (float*)smem;                // EPI2: [1024] scores
  float* Zs = (float*)(smem + 4096);         // EPI2: [256][32] f32
  float (*sred)[2] = (float(*)[2])smem;      // EPI1: [256][2]

  if constexpr (EPI == 2) {
    for (int i = tid; i < 1024; i += 512) s_sc[i] = sc[m0 * 4 + i];
  }

  // wave-uniform fragment base pointers (saddr form), per-lane voff = l*16 + S*1024
  const char* Ab[4];
  const char* Bb[4];
#pragma unroll
  for (int m = 0; m < 4; ++m) {
    int R = (int)(m0 >> 4) + wm * 4 + m;
    Ab[m] = (const char*)Af + (size_t)R * NS * 1024;
  }
#pragma unroll
  for (int n = 0; n < 4; ++n) {
    int P = nt * 8 + wn * 4 + n;
    Bb[n] = (const char*)Bf + (size_t)P * NS * 1024;
  }
  int voff = l * 16;

  f32x4 zero = {0.f, 0.f, 0.f, 0.f};
  f32x4 acc[4][4];
#pragma unroll
  for (int m = 0; m < 4; ++m)
#pragma unroll
    for (int n = 0; n < 4; ++n) acc[m][n] = zero;

#define LD4(dst, bases, add)                                              \
  do {                                                                    \
    _Pragma("unroll") for (int i_ = 0; i_ < 4; ++i_)                      \
        dst[i_] = *(const short8*)(bases[i_] + voff + (add));             \
  } while (0)
#define MF(A_, B_)                                                        \
  do {                                                                    \
    _Pragma("unroll") for (int m_ = 0; m_ < 4; ++m_)                      \
        _Pragma("unroll") for (int n_ = 0; n_ < 4; ++n_) acc[m_][n_] =    \
            __builtin_amdgcn_mfma_f32_16x16x32_bf16(A_[m_], B_[n_],       \
                                                    acc[m_][n_], 0, 0, 0);\
  } while (0)

  short8 a0[4], b0[4], a1[4], b1[4];
  LD4(a0, Ab, 0);
  LD4(b0, Bb, 0);
  int off = 0;
  for (int s = 0; s + 2 < NS; s += 2) {
    LD4(a1, Ab, off + 1024);
    LD4(b1, Bb, off + 1024);
    MF(a0, b0);
    LD4(a0, Ab, off + 2048);
    LD4(b0, Bb, off + 2048);
    MF(a1, b1);
    off += 2048;
  }
  LD4(a1, Ab, off + 1024);
  LD4(b1, Bb, off + 1024);
  MF(a0, b0);
  MF(a1, b1);
#undef LD4
#undef MF

  if constexpr (EPI == 0) {
#pragma unroll
    for (int n = 0; n < 4; ++n) {
      int col = nt * 128 + wn * 64 + n * 16 + (l & 15);
      float bb = bias[col];
#pragma unroll
      for (int m = 0; m < 4; ++m) {
        long rowb = m0 + wm * 64 + m * 16 + ((l >> 4) << 2);
#pragma unroll
        for (int r = 0; r < 4; ++r)
          outb[(rowb + r) * 512 + col] = f2b(acc[m][n][r] + bb);
      }
    }
  } else if constexpr (EPI == 1) {
    float part[4][4] = {};
#pragma unroll
    for (int n = 0; n < 4; ++n) {
      int col = nt * 128 + wn * 64 + n * 16 + (l & 15);
      float bb = bias[col];
#pragma unroll
      for (int m = 0; m < 4; ++m) {
        long rowb = m0 + wm * 64 + m * 16 + ((l >> 4) << 2);
#pragma unroll
        for (int r = 0; r < 4; ++r) {
          float kv = acc[m][n][r] + bb;
          part[m][r] += kv * b2f(Qb[(rowb + r) * 512 + col]);
        }
      }
    }
#pragma unroll
    for (int m = 0; m < 4; ++m)
#pragma unroll
      for (int r = 0; r < 4; ++r) {
        float s = part[m][r];
        s += __shfl_xor(s, 1);
        s += __shfl_xor(s, 2);
        s += __shfl_xor(s, 4);
        s += __shfl_xor(s, 8);
        if ((l & 15) == 0)
          sred[wm * 64 + m * 16 + ((l >> 4) << 2) + r][wn] = s;
      }
    __syncthreads();
    if (tid < 256) sc[(m0 + tid) * 4 + nt] = sred[tid][0] + sred[tid][1];
  } else {
    __syncthreads();                         // s_sc visible to all waves
#pragma unroll
    for (int n = 0; n < 4; ++n) {
      int pl = wn * 64 + n * 16 + (l & 15);  // local permuted col, p = 4d+h
      int pg = nt * 128 + pl;
      int h = pg & 3;
      float bb = bias[(pg & 3) * 1024 + (pg >> 2)];
#pragma unroll
      for (int m = 0; m < 4; ++m) {
        int rl = wm * 64 + m * 16 + ((l >> 4) << 2);
#pragma unroll
        for (int r = 0; r < 4; ++r) {
          float z = s_sc[(rl + r) * 4 + h] * (acc[m][n][r] + bb);
          z = fmaxf(z, __shfl_xor(z, 1));    // max over heads (adjacent p)
          z = fmaxf(z, __shfl_xor(z, 2));
          if ((l & 3) == 0) Zs[(rl + r) * 32 + (pl >> 2)] = z;
        }
      }
    }
    __syncthreads();
#pragma unroll
    for (int it = 0; it < 4; ++it) {         // coalesced float4 stores, 256x32 f32
      int i = it * 512 + tid;
      int row = i >> 3, q = i & 7;
      f32x4 v = *(const f32x4*)&Zs[row * 32 + q * 4];
      *(f32x4*)&Z[(m0 + row) * 1024 + nt * 32 + q * 4] = v;
    }
  }
}

// ---------------- fallback (only if ws too small): fp32, correct but slow ----------------
__global__ __launch_bounds__(256) void naive_k(
    const float* __restrict__ Xd, const float* __restrict__ Xo,
    const float* __restrict__ Wq, const float* __restrict__ bq,
    const float* __restrict__ Wk, const float* __restrict__ bk,
    const float* __restrict__ Wv, const float* __restrict__ bv,
    float* __restrict__ Z) {
  int i = blockIdx.x, t = threadIdx.x;
  __shared__ float xd[1024], xo[512], s[4];
  for (int j = t; j < 1024; j += 256) xd[j] = Xd[(size_t)i * 1024 + j];
  for (int j = t; j < 512; j += 256) xo[j] = Xo[(size_t)i * 512 + j];
  if (t < 4) s[t] = 0.f;
  __syncthreads();
  for (int c = t; c < 512; c += 256) {
    float q = bq[c], k = bk[c];
    for (int j = 0; j < 512; ++j) q += xo[j] * Wq[(size_t)j * 512 + c];
    for (int j = 0; j < 1024; ++j) k += xd[j] * Wk[(size_t)j * 512 + c];
    atomicAdd(&s[c >> 7], q * k);
  }
  __syncthreads();
  for (int d = t; d < 1024; d += 256) {
    float z = -INFINITY;
    for (int h = 0; h < 4; ++h) {
      float v = bv[h * 1024 + d];
      for (int j = 0; j < 1024; ++j) v += xd[j] * Wv[(size_t)j * 4096 + h * 1024 + d];
      z = fmaxf(z, s[h] * v);
    }
    Z[(size_t)i * 1024 + d] = z;
  }
}

extern "C" void kernel_launch(void* const* d_in, const int* in_sizes, int n_in,
                              void* d_out, int out_size, void* d_ws, size_t ws_size,
                              hipStream_t stream) {
  const float* Xd = (const float*)d_in[0];
  const float* Xo = (const float*)d_in[1];
  const float* Wq = (const float*)d_in[2];
  const float* bq = (const float*)d_in[3];
  const float* Wk = (const float*)d_in[4];
  const float* bk = (const float*)d_in[5];
  const float* Wv = (const float*)d_in[6];
  const float* bv = (const float*)d_in[7];
  float* Z = (float*)d_out;
  long N = in_sizes[0] / 1024;

  size_t sz_Xd = (size_t)N * 1024 * 2, sz_Xo = (size_t)N * 512 * 2;
  size_t sz_Wq = (size_t)512 * 512 * 2, sz_Wk = (size_t)512 * 1024 * 2;
  size_t sz_Wv = (size_t)4096 * 1024 * 2;
  size_t sz_Qb = (size_t)N * 512 * 2, sz_sc = (size_t)N * 4 * 4;
  size_t o_Xo = sz_Xd, o_Wq = o_Xo + sz_Xo, o_Wk = o_Wq + sz_Wq,
         o_Wv = o_Wk + sz_Wk, o_Qb = o_Wv + sz_Wv, o_sc = o_Qb + sz_Qb;
  size_t need = o_sc + sz_sc;

  if (ws_size < need || (N % 256) != 0) {
    naive_k<<<(int)N, 256, 0, stream>>>(Xd, Xo, Wq, bq, Wk, bk, Wv, bv, Z);
    return;
  }

  char* w = (char*)d_ws;
  unsigned short* Xd_f = (unsigned short*)w;
  unsigned short* Xo_f = (unsigned short*)(w + o_Xo);
  unsigned short* Wq_f = (unsigned short*)(w + o_Wq);
  unsigned short* Wk_f = (unsigned short*)(w + o_Wk);
  unsigned short* Wv_f = (unsigned short*)(w + o_Wv);
  unsigned short* Qb   = (unsigned short*)(w + o_Qb);
  float* sc = (float*)(w + o_sc);

  pack_a_k<<<(int)(N / 16), 256, 0, stream>>>(Xd, Xd_f, 1024);
  pack_a_k<<<(int)(N / 16), 256, 0, stream>>>(Xo, Xo_f, 512);
  pack_b_k<0><<<dim3(32, 4), 256, 0, stream>>>(Wq, Wq_f, 512, 512);
  pack_b_k<0><<<dim3(32, 8), 256, 0, stream>>>(Wk, Wk_f, 1024, 512);
  pack_b_k<1><<<dim3(256, 8), 256, 0, stream>>>(Wv, Wv_f, 1024, 4096);

  int mt = (int)(N / 256);
  gemm_flat<512, 4, 0><<<mt * 4, 512, 0, stream>>>(Xo_f, Wq_f, bq, nullptr, Qb,
                                                   nullptr, nullptr);
  gemm_flat<1024, 4, 1><<<mt * 4, 512, 0, stream>>>(Xd_f, Wk_f, bk, Qb, nullptr,
                                                    sc, nullptr);
  gemm_flat<1024, 32, 2><<<mt * 32, 512, 0, stream>>>(Xd_f, Wv_f, bv, nullptr,
                                                      nullptr, sc, Z);
}

// Round 6
// 477.207 us; speedup vs baseline: 1.4832x; 1.4832x over previous
//
#include <hip/hip_runtime.h>

typedef __attribute__((ext_vector_type(8))) short short8;
typedef __attribute__((ext_vector_type(4))) float f32x4;

// async global->LDS, 16B per lane. LDS dest = wave-uniform base (+ lane*16 by HW).
#define GLL16(gp, lp) __builtin_amdgcn_global_load_lds( \
    (__attribute__((address_space(1))) void*)(gp), \
    (__attribute__((address_space(3))) void*)(lp), 16, 0, 0)

__device__ __forceinline__ unsigned short f2b(float f) {
  unsigned int u = __builtin_bit_cast(unsigned int, f);
  u += 0x7fffu + ((u >> 16) & 1u);   // RNE; inputs are finite
  return (unsigned short)(u >> 16);
}
__device__ __forceinline__ float b2f(unsigned short s) {
  unsigned int u = ((unsigned int)s) << 16;
  return __builtin_bit_cast(float, u);
}

// ---------------- f32 -> bf16 straight convert (Xd, Xo) ----------------
__global__ __launch_bounds__(256) void conv_k(const float* __restrict__ in,
                                              short8* __restrict__ out, long n8) {
  for (long i = (long)blockIdx.x * 256 + threadIdx.x; i < n8;
       i += (long)gridDim.x * 256) {
    const float4* p = (const float4*)in + 2 * i;
    float4 a = p[0], b = p[1];
    short8 v;
    v[0] = (short)f2b(a.x); v[1] = (short)f2b(a.y);
    v[2] = (short)f2b(a.z); v[3] = (short)f2b(a.w);
    v[4] = (short)f2b(b.x); v[5] = (short)f2b(b.y);
    v[6] = (short)f2b(b.z); v[7] = (short)f2b(b.w);
    out[i] = v;
  }
}

// ------------- transpose+convert weights: in (K x C f32) -> out (C x K bf16) -------------
// inter=1 (Wv): output row for input col c = 4*(c&1023) + (c>>10)  (p = 4d+h head-interleave)
__global__ __launch_bounds__(256) void tconv_k(const float* __restrict__ in,
                                               unsigned short* __restrict__ out,
                                               int K, int C, int inter) {
  __shared__ float t[32][33];
  int k0 = blockIdx.x * 32, c0 = blockIdx.y * 32;
  int tx = threadIdx.x & 31, ty = threadIdx.x >> 5;
#pragma unroll
  for (int p = 0; p < 4; ++p)
    t[ty + p * 8][tx] = in[(size_t)(k0 + ty + p * 8) * C + c0 + tx];
  __syncthreads();
#pragma unroll
  for (int p = 0; p < 4; ++p) {
    int c = ty + p * 8;
    int gc = c0 + c;
    int orow = inter ? ((gc & 1023) * 4 + (gc >> 10)) : gc;
    out[(size_t)orow * K + k0 + tx] = f2b(t[tx][c]);
  }
}

// ======== 256x256 BK=64 8-wave QUADRANT-PHASE V-GEMM (faithful 8-phase template) ========
// Per phase: whole block computes one 128x128 C-quadrant (16 MFMA/wave).
// Half-matrix ring (8 x 16KB slots, 128KB): stage order per tile [Ah0,Bh0,Bh1,Ah1]
// => reads at global phase g need only halves <= H[g+1]; vmcnt(4)+barrier each phase
// certifies exactly that. Never drains in steady state (T4). setprio around MFMA (T5).
// A: N x KD bf16 rows. Bt: 4096 permuted cols as rows (p=4d+h), stride KD.
// Z[row][d] = max_h sc[row][h] * (acc + bv).
template <int KD>
__global__ __launch_bounds__(512, 2) void gemm_v8p(
    const unsigned short* __restrict__ A, const unsigned short* __restrict__ Bt,
    const float* __restrict__ bias, const float* __restrict__ sc,
    float* __restrict__ Z) {
  __shared__ __align__(16) char lds[131072];   // A slots [0..3]*16KB, B slots at +64KB
  __shared__ float s_sc[1024];

  constexpr int NKT = KD / 64;
  int tid = threadIdx.x;
  int bid = blockIdx.x;
  int cpx = gridDim.x >> 3;                    // grid % 8 == 0 (bijective XCD swizzle)
  int lb = (bid & 7) * cpx + (bid >> 3);
  int mtile = lb >> 4, nt0 = lb & 15;
  long m0 = (long)mtile * 256;
  int l = tid & 63, wid = tid >> 6, wm = wid >> 2, wn = wid & 3;

  for (int i = tid; i < 1024; i += 512) s_sc[i] = sc[m0 * 4 + i];

  // staging source mapping (inverse of read swizzle), verified R1-R4:
  // LDS[row][pos] (pos = 16B chunk 0..7) holds source chunk pos^(row&7).
  int rowg = tid >> 3;                          // row within 64-row GLL group
  int swz = (tid & 7) ^ (rowg & 7);
  const char* aSrc = (const char*)(A + m0 * KD) + (long)rowg * (KD * 2) + swz * 16;
  const char* bSrc = (const char*)(Bt + (long)nt0 * 256 * KD) + (long)rowg * (KD * 2) + swz * 16;
  char* ldsb = (char*)lds;
  int dstOff = wid * 1024;                      // wave-uniform dest component

  // stage one half-matrix (128 rows x 64 k = 16KB) = 2 x GLL16
  auto stageA = [&](int hh, int tt) {
    char* base = ldsb + (((tt & 1) * 2 + hh) * 16384) + dstOff;
    const char* s = aSrc + (long)(hh * 128) * (KD * 2) + tt * 128;
    GLL16(s, base);
    GLL16(s + (long)64 * (KD * 2), base + 8192);
  };
  auto stageB = [&](int hh, int tt) {
    char* base = ldsb + 65536 + (((tt & 1) * 2 + hh) * 16384) + dstOff;
    const char* s = bSrc + (long)(hh * 128) * (KD * 2) + tt * 128;
    GLL16(s, base);
    GLL16(s + (long)64 * (KD * 2), base + 8192);
  };

  // read offsets (within a 16KB half), swizzled; lrow in [0,128)
  int ar = l & 15, kcl = l >> 4;
  int aoff[4][2], boff[2][2];
#pragma unroll
  for (int m = 0; m < 4; ++m) {
    int lrow = wm * 64 + m * 16 + ar;
#pragma unroll
    for (int ks = 0; ks < 2; ++ks)
      aoff[m][ks] = lrow * 128 + (((ks * 4 + kcl) ^ (lrow & 7)) << 4);
  }
#pragma unroll
  for (int n = 0; n < 2; ++n) {
    int lcol = wn * 32 + n * 16 + ar;
#pragma unroll
    for (int ks = 0; ks < 2; ++ks)
      boff[n][ks] = lcol * 128 + (((ks * 4 + kcl) ^ (lcol & 7)) << 4);
  }

  f32x4 zero = {0.f, 0.f, 0.f, 0.f};
  f32x4 acc[4][8];                              // [quad mh*2+nh][m*2+n]
#pragma unroll
  for (int q = 0; q < 4; ++q)
#pragma unroll
    for (int f = 0; f < 8; ++f) acc[q][f] = zero;

  short8 a[4][2], b0[2][2], b1[2][2];

#define READ_A(slotbase)                                                   \
  _Pragma("unroll") for (int m_ = 0; m_ < 4; ++m_)                         \
      _Pragma("unroll") for (int k_ = 0; k_ < 2; ++k_)                     \
          a[m_][k_] = *(const short8*)((slotbase) + aoff[m_][k_]);
#define READ_B(dst, slotbase)                                              \
  _Pragma("unroll") for (int n_ = 0; n_ < 2; ++n_)                         \
      _Pragma("unroll") for (int k_ = 0; k_ < 2; ++k_)                     \
          dst[n_][k_] = *(const short8*)((slotbase) + boff[n_][k_]);
#define MFMA_Q(q, bq)                                                      \
  __builtin_amdgcn_s_setprio(1);                                           \
  _Pragma("unroll") for (int m_ = 0; m_ < 4; ++m_)                         \
      _Pragma("unroll") for (int n_ = 0; n_ < 2; ++n_)                     \
          _Pragma("unroll") for (int k_ = 0; k_ < 2; ++k_)                 \
              acc[q][m_ * 2 + n_] = __builtin_amdgcn_mfma_f32_16x16x32_bf16( \
                  a[m_][k_], bq[n_][k_], acc[q][m_ * 2 + n_], 0, 0, 0);    \
  __builtin_amdgcn_s_setprio(0);
#define WAITV()                                                            \
  if (t < NKT - 1) { asm volatile("s_waitcnt vmcnt(4)" ::: "memory"); }    \
  else             { asm volatile("s_waitcnt vmcnt(0)" ::: "memory"); }
#define BAR() __builtin_amdgcn_s_barrier()
#define LGKM0() asm volatile("s_waitcnt lgkmcnt(0)" ::: "memory")

  // prologue: tile 0's four halves in stage order [Ah0, Bh0, Bh1, Ah1]
  stageA(0, 0); stageB(0, 0); stageB(1, 0); stageA(1, 0);
  asm volatile("s_waitcnt vmcnt(4)" ::: "memory");
  BAR();

  for (int t = 0; t < NKT; ++t) {
    char* aS = ldsb + ((t & 1) * 2) * 16384;          // Ah0 slot
    char* bS = ldsb + 65536 + ((t & 1) * 2) * 16384;  // Bh0 slot
    bool st = (t + 1 < NKT);

    // phase 0: q00 — read Ah0 + Bh0; stage Ah0[t+1]
    READ_A(aS);
    READ_B(b0, bS);
    if (st) stageA(0, t + 1);
    WAITV(); BAR(); LGKM0();
    MFMA_Q(0, b0);
    BAR();

    // phase 1: q01 — read Bh1; stage Bh0[t+1]
    READ_B(b1, bS + 16384);
    if (st) stageB(0, t + 1);
    WAITV(); BAR(); LGKM0();
    MFMA_Q(1, b1);
    BAR();

    // phase 2: q10 — read Ah1 (overwrite a); stage Bh1[t+1]
    READ_A(aS + 16384);
    if (st) stageB(1, t + 1);
    WAITV(); BAR(); LGKM0();
    MFMA_Q(2, b0);
    BAR();

    // phase 3: q11 — no reads; stage Ah1[t+1]
    if (st) stageA(1, t + 1);
    WAITV(); BAR();
    MFMA_Q(3, b1);
    BAR();
  }
#undef READ_A
#undef READ_B
#undef MFMA_Q
#undef WAITV
#undef BAR
#undef LGKM0

  // ---------------- fused epilogue: scale by scores, max over heads ----------------
  __syncthreads();
  float* Zs = (float*)ldsb;                     // 256 x 64 f32 = 64 KB
#pragma unroll
  for (int qm = 0; qm < 2; ++qm)
#pragma unroll
    for (int qn = 0; qn < 2; ++qn) {
      int q = qm * 2 + qn;
#pragma unroll
      for (int n = 0; n < 2; ++n) {
        int pl = qn * 128 + wn * 32 + n * 16 + (l & 15);  // permuted col, p=4d+h
        int pg = nt0 * 256 + pl;
        int h = pl & 3;
        float bb = bias[(pg & 3) * 1024 + (pg >> 2)];
#pragma unroll
        for (int m = 0; m < 4; ++m) {
          int rl = qm * 128 + wm * 64 + m * 16 + ((l >> 4) << 2);
#pragma unroll
          for (int r = 0; r < 4; ++r) {
            float z = s_sc[(rl + r) * 4 + h] * (acc[q][m * 2 + n][r] + bb);
            z = fmaxf(z, __shfl_xor(z, 1));     // max over heads (adjacent p)
            z = fmaxf(z, __shfl_xor(z, 2));
            if ((l & 3) == 0) Zs[(rl + r) * 64 + (pl >> 2)] = z;
          }
        }
      }
    }
  __syncthreads();
#pragma unroll
  for (int it = 0; it < 8; ++it) {              // coalesced float4 stores
    int i = it * 512 + tid;
    int row = i >> 4, d4 = i & 15;
    f32x4 v = *(const f32x4*)&Zs[row * 64 + d4 * 4];
    *(f32x4*)&Z[(m0 + row) * 1024 + nt0 * 64 + d4 * 4] = v;
  }
}

// ---------------- 128x128 GEMM, BK=64, 4 waves (m97 structure) — Q and K ----------------
// EPI 0: out bf16 = acc + bias[col]            (Q GEMM)
// EPI 1: scores[row][ntile] = sum_col (acc+bk[col]) * Qb[row][col]   (K GEMM + reduce)
template <int KD, int EPI>
__global__ __launch_bounds__(256) void gemm_k(
    const unsigned short* __restrict__ A, const unsigned short* __restrict__ Bt,
    const float* __restrict__ bias, const unsigned short* __restrict__ Qb,
    unsigned short* __restrict__ outb, float* __restrict__ sc) {
  __shared__ __align__(16) unsigned short As[128 * 64];
  __shared__ __align__(16) unsigned short Bs[128 * 64];
  __shared__ float sred[128][2];

  int tid = threadIdx.x;
  int bid = blockIdx.x;
  int ntile = bid & 3, mtile = bid >> 2;
  int l = tid & 63, wid = tid >> 6, wm = wid >> 1, wn = wid & 1;
  int m0 = mtile * 128;

  const unsigned short* Ab = A + (size_t)m0 * KD;
  const unsigned short* Bb = Bt + (size_t)ntile * 128 * KD;

  f32x4 zero = {0.f, 0.f, 0.f, 0.f};
  f32x4 acc[4][4];
#pragma unroll
  for (int m = 0; m < 4; ++m)
#pragma unroll
    for (int n = 0; n < 4; ++n) acc[m][n] = zero;

  for (int kt = 0; kt < KD / 64; ++kt) {
    const unsigned short* sA = Ab + kt * 64;
    const unsigned short* sB = Bb + kt * 64;
#pragma unroll
    for (int p = 0; p < 4; ++p) {
      int row = p * 32 + wid * 8 + (l >> 3);
      int sch = (l & 7) ^ (row & 7);
      GLL16((const char*)(sA + (size_t)row * KD) + sch * 16,
            (char*)As + p * 4096 + wid * 1024);
    }
#pragma unroll
    for (int p = 0; p < 4; ++p) {
      int row = p * 32 + wid * 8 + (l >> 3);
      int sch = (l & 7) ^ (row & 7);
      GLL16((const char*)(sB + (size_t)row * KD) + sch * 16,
            (char*)Bs + p * 4096 + wid * 1024);
    }
    __syncthreads();
#pragma unroll
    for (int ks = 0; ks < 2; ++ks) {
      short8 af[4], bfr[4];
#pragma unroll
      for (int m = 0; m < 4; ++m) {
        int row = wm * 64 + m * 16 + (l & 15);
        int kc = ks * 4 + (l >> 4);
        af[m] = *(const short8*)((const char*)As + row * 128 +
                                 ((kc ^ (row & 7)) << 4));
      }
#pragma unroll
      for (int n = 0; n < 4; ++n) {
        int row = wn * 64 + n * 16 + (l & 15);
        int kc = ks * 4 + (l >> 4);
        bfr[n] = *(const short8*)((const char*)Bs + row * 128 +
                                  ((kc ^ (row & 7)) << 4));
      }
#pragma unroll
      for (int m = 0; m < 4; ++m)
#pragma unroll
        for (int n = 0; n < 4; ++n)
          acc[m][n] = __builtin_amdgcn_mfma_f32_16x16x32_bf16(af[m], bfr[n],
                                                              acc[m][n], 0, 0, 0);
    }
    __syncthreads();
  }

  if constexpr (EPI == 0) {
#pragma unroll
    for (int n = 0; n < 4; ++n) {
      int col = ntile * 128 + wn * 64 + n * 16 + (l & 15);
      float bb = bias[col];
#pragma unroll
      for (int m = 0; m < 4; ++m) {
        int rowb = m0 + wm * 64 + m * 16 + ((l >> 4) << 2);
#pragma unroll
        for (int r = 0; r < 4; ++r)
          outb[(size_t)(rowb + r) * 512 + col] = f2b(acc[m][n][r] + bb);
      }
    }
  } else {
    float part[4][4] = {};
#pragma unroll
    for (int n = 0; n < 4; ++n) {
      int col = ntile * 128 + wn * 64 + n * 16 + (l & 15);
      float bb = bias[col];
#pragma unroll
      for (int m = 0; m < 4; ++m) {
        int rowb = m0 + wm * 64 + m * 16 + ((l >> 4) << 2);
#pragma unroll
        for (int r = 0; r < 4; ++r) {
          float kv = acc[m][n][r] + bb;
          part[m][r] += kv * b2f(Qb[(size_t)(rowb + r) * 512 + col]);
        }
      }
    }
#pragma unroll
    for (int m = 0; m < 4; ++m)
#pragma unroll
      for (int r = 0; r < 4; ++r) {
        float s = part[m][r];
        s += __shfl_xor(s, 1);
        s += __shfl_xor(s, 2);
        s += __shfl_xor(s, 4);
        s += __shfl_xor(s, 8);
        if ((l & 15) == 0)
          sred[wm * 64 + m * 16 + ((l >> 4) << 2) + r][wn] = s;
      }
    __syncthreads();
    if (tid < 128) sc[(size_t)(m0 + tid) * 4 + ntile] = sred[tid][0] + sred[tid][1];
  }
}

// ---------------- fallback (only if ws too small): fp32, correct but slow ----------------
__global__ __launch_bounds__(256) void naive_k(
    const float* __restrict__ Xd, const float* __restrict__ Xo,
    const float* __restrict__ Wq, const float* __restrict__ bq,
    const float* __restrict__ Wk, const float* __restrict__ bk,
    const float* __restrict__ Wv, const float* __restrict__ bv,
    float* __restrict__ Z) {
  int i = blockIdx.x, t = threadIdx.x;
  __shared__ float xd[1024], xo[512], s[4];
  for (int j = t; j < 1024; j += 256) xd[j] = Xd[(size_t)i * 1024 + j];
  for (int j = t; j < 512; j += 256) xo[j] = Xo[(size_t)i * 512 + j];
  if (t < 4) s[t] = 0.f;
  __syncthreads();
  for (int c = t; c < 512; c += 256) {
    float q = bq[c], k = bk[c];
    for (int j = 0; j < 512; ++j) q += xo[j] * Wq[(size_t)j * 512 + c];
    for (int j = 0; j < 1024; ++j) k += xd[j] * Wk[(size_t)j * 512 + c];
    atomicAdd(&s[c >> 7], q * k);
  }
  __syncthreads();
  for (int d = t; d < 1024; d += 256) {
    float z = -INFINITY;
    for (int h = 0; h < 4; ++h) {
      float v = bv[h * 1024 + d];
      for (int j = 0; j < 1024; ++j) v += xd[j] * Wv[(size_t)j * 4096 + h * 1024 + d];
      z = fmaxf(z, s[h] * v);
    }
    Z[(size_t)i * 1024 + d] = z;
  }
}

extern "C" void kernel_launch(void* const* d_in, const int* in_sizes, int n_in,
                              void* d_out, int out_size, void* d_ws, size_t ws_size,
                              hipStream_t stream) {
  const float* Xd = (const float*)d_in[0];
  const float* Xo = (const float*)d_in[1];
  const float* Wq = (const float*)d_in[2];
  const float* bq = (const float*)d_in[3];
  const float* Wk = (const float*)d_in[4];
  const float* bk = (const float*)d_in[5];
  const float* Wv = (const float*)d_in[6];
  const float* bv = (const float*)d_in[7];
  float* Z = (float*)d_out;
  long N = in_sizes[0] / 1024;

  size_t sz_Xd = (size_t)N * 1024 * 2, sz_Xo = (size_t)N * 512 * 2;
  size_t sz_Wq = (size_t)512 * 512 * 2, sz_Wk = (size_t)512 * 1024 * 2;
  size_t sz_Wv = (size_t)4096 * 1024 * 2;
  size_t sz_Qb = (size_t)N * 512 * 2, sz_sc = (size_t)N * 4 * 4;
  size_t o_Xo = sz_Xd, o_Wq = o_Xo + sz_Xo, o_Wk = o_Wq + sz_Wq,
         o_Wv = o_Wk + sz_Wk, o_Qb = o_Wv + sz_Wv, o_sc = o_Qb + sz_Qb;
  size_t need = o_sc + sz_sc;

  if (ws_size < need || (N % 256) != 0) {
    naive_k<<<(int)N, 256, 0, stream>>>(Xd, Xo, Wq, bq, Wk, bk, Wv, bv, Z);
    return;
  }

  char* w = (char*)d_ws;
  unsigned short* Xd_b = (unsigned short*)w;
  unsigned short* Xo_b = (unsigned short*)(w + o_Xo);
  unsigned short* Wq_t = (unsigned short*)(w + o_Wq);
  unsigned short* Wk_t = (unsigned short*)(w + o_Wk);
  unsigned short* Wv_p = (unsigned short*)(w + o_Wv);
  unsigned short* Qb   = (unsigned short*)(w + o_Qb);
  float* sc = (float*)(w + o_sc);

  conv_k<<<2048, 256, 0, stream>>>(Xd, (short8*)Xd_b, N * 1024 / 8);
  conv_k<<<2048, 256, 0, stream>>>(Xo, (short8*)Xo_b, N * 512 / 8);
  tconv_k<<<dim3(16, 16), 256, 0, stream>>>(Wq, Wq_t, 512, 512, 0);
  tconv_k<<<dim3(32, 16), 256, 0, stream>>>(Wk, Wk_t, 1024, 512, 0);
  tconv_k<<<dim3(32, 128), 256, 0, stream>>>(Wv, Wv_p, 1024, 4096, 1);

  int mt = (int)(N / 128);
  gemm_k<512, 0><<<mt * 4, 256, 0, stream>>>(Xo_b, Wq_t, bq, nullptr, Qb, nullptr);
  gemm_k<1024, 1><<<mt * 4, 256, 0, stream>>>(Xd_b, Wk_t, bk, Qb, nullptr, sc);
  gemm_v8p<1024><<<(int)(N / 256) * 16, 512, 0, stream>>>(Xd_b, Wv_p, bv, sc, Z);
}

// Round 7
// 471.286 us; speedup vs baseline: 1.5018x; 1.0126x over previous
//
#include <hip/hip_runtime.h>

typedef __attribute__((ext_vector_type(8))) short short8;
typedef __attribute__((ext_vector_type(4))) float f32x4;

// async global->LDS, 16B per lane. LDS dest = wave-uniform base (+ lane*16 by HW).
#define GLL16(gp, lp) __builtin_amdgcn_global_load_lds( \
    (__attribute__((address_space(1))) void*)(gp), \
    (__attribute__((address_space(3))) void*)(lp), 16, 0, 0)

__device__ __forceinline__ unsigned short f2b(float f) {
  unsigned int u = __builtin_bit_cast(unsigned int, f);
  u += 0x7fffu + ((u >> 16) & 1u);   // RNE; inputs are finite
  return (unsigned short)(u >> 16);
}
__device__ __forceinline__ float b2f(unsigned short s) {
  unsigned int u = ((unsigned int)s) << 16;
  return __builtin_bit_cast(float, u);
}

// ---------------- f32 -> bf16 straight convert (Xd, Xo) ----------------
__global__ __launch_bounds__(256) void conv_k(const float* __restrict__ in,
                                              short8* __restrict__ out, long n8) {
  for (long i = (long)blockIdx.x * 256 + threadIdx.x; i < n8;
       i += (long)gridDim.x * 256) {
    const float4* p = (const float4*)in + 2 * i;
    float4 a = p[0], b = p[1];
    short8 v;
    v[0] = (short)f2b(a.x); v[1] = (short)f2b(a.y);
    v[2] = (short)f2b(a.z); v[3] = (short)f2b(a.w);
    v[4] = (short)f2b(b.x); v[5] = (short)f2b(b.y);
    v[6] = (short)f2b(b.z); v[7] = (short)f2b(b.w);
    out[i] = v;
  }
}

// ------------- transpose+convert weights: in (K x C f32) -> out (C x K bf16) -------------
// inter=1 (Wv): output row for input col c = 4*(c&1023) + (c>>10)  (p = 4d+h head-interleave)
__global__ __launch_bounds__(256) void tconv_k(const float* __restrict__ in,
                                               unsigned short* __restrict__ out,
                                               int K, int C, int inter) {
  __shared__ float t[32][33];
  int k0 = blockIdx.x * 32, c0 = blockIdx.y * 32;
  int tx = threadIdx.x & 31, ty = threadIdx.x >> 5;
#pragma unroll
  for (int p = 0; p < 4; ++p)
    t[ty + p * 8][tx] = in[(size_t)(k0 + ty + p * 8) * C + c0 + tx];
  __syncthreads();
#pragma unroll
  for (int p = 0; p < 4; ++p) {
    int c = ty + p * 8;
    int gc = c0 + c;
    int orow = inter ? ((gc & 1023) * 4 + (gc >> 10)) : gc;
    out[(size_t)orow * K + k0 + tx] = f2b(t[tx][c]);
  }
}

// ======== 256x256 BK=64 quadrant-phase GEMM, cross-phase read pipeline ========
// Half order per tile [A0,B0,B1,A1]; quadrants q0(A0,B0) q1(A0,B1) q2(A1,B0) q3(A1,B1).
// Phase p: {stage 1 half of t+1; vmcnt(4); barrier; ds_read a FUTURE operand; MFMA q_p}.
// Reads per phase: p0:B1[t](4) p1:A1[t](8) p2:A0[t+1](8) p3:B0[t+1](4) — every MFMA's
// operands were read >=1 phase earlier (compiler emits counted lgkm automatically).
// One barrier/phase: every GLL write targets a slot whose last ds_read was >=6 phases ago.
// EPI 0: Qb bf16 = acc+bias. EPI 1: sc[row][head] = sum_col (acc+bias)*Qb (2 heads/block).
// EPI 2: Z[row][d] = max_h sc[row][h]*(acc+bv), cols head-interleaved p=4d+h.
template <int KD, int NTI, int EPI>
__global__ __launch_bounds__(512, 2) void gemm_p(
    const unsigned short* __restrict__ A, const unsigned short* __restrict__ Bt,
    const float* __restrict__ bias, const unsigned short* __restrict__ Qb,
    unsigned short* __restrict__ outb, float* __restrict__ sc,
    float* __restrict__ Z) {
  __shared__ __align__(16) char lds[131072];   // A slots 0..3 x16KB, B at +64KB
  __shared__ float s_sc[1024];

  constexpr int NKT = KD / 64;
  int tid = threadIdx.x;
  int bid = blockIdx.x;
  int cpx = gridDim.x >> 3;                    // grid % 8 == 0 (bijective XCD swizzle)
  int lb = (bid & 7) * cpx + (bid >> 3);
  int mtile = lb / NTI, nt0 = lb % NTI;
  long m0 = (long)mtile * 256;
  int l = tid & 63, wid = tid >> 6, wm = wid >> 2, wn = wid & 3;

  // staging source mapping (inverse of read swizzle), verified R1-R6:
  // LDS[row][pos16B] holds source chunk pos^(row&7).
  int rowg = tid >> 3;
  int swz = (tid & 7) ^ (rowg & 7);
  const char* aSrc = (const char*)(A + m0 * KD) + (long)rowg * (KD * 2) + swz * 16;
  const char* bSrc = (const char*)(Bt + (long)nt0 * 256 * KD) + (long)rowg * (KD * 2) + swz * 16;
  char* ldsb = (char*)lds;
  int dstOff = wid * 1024;

  auto stageA = [&](int hh, int tt) {
    char* base = ldsb + ((tt & 1) * 32768 + hh * 16384) + dstOff;
    const char* s = aSrc + (long)(hh * 128) * (KD * 2) + tt * 128;
    GLL16(s, base);
    GLL16(s + (long)64 * (KD * 2), base + 8192);
  };
  auto stageB = [&](int hh, int tt) {
    char* base = ldsb + 65536 + ((tt & 1) * 32768 + hh * 16384) + dstOff;
    const char* s = bSrc + (long)(hh * 128) * (KD * 2) + tt * 128;
    GLL16(s, base);
    GLL16(s + (long)64 * (KD * 2), base + 8192);
  };

  // thread-local read offsets (swizzled). row&7 == ar&7 since 16|64-multiples drop out.
  int ar = l & 15, kcl = l >> 4;
  int x0 = ((kcl ^ (ar & 7)) << 4);
  int x1 = (((4 | kcl) ^ (ar & 7)) << 4);
  int thrA = (wm * 64 + ar) * 128;
  int thrB = (wn * 32 + ar) * 128;

  short8 aA[4][2], aB[4][2], b0[2][2], b1[2][2];

#define RD_A(dst, slotoff)                                                  \
  do {                                                                      \
    const char* p_ = ldsb + (slotoff) + thrA;                               \
    _Pragma("unroll") for (int m_ = 0; m_ < 4; ++m_) {                      \
      dst[m_][0] = *(const short8*)(p_ + x0 + m_ * 2048);                   \
      dst[m_][1] = *(const short8*)(p_ + x1 + m_ * 2048);                   \
    }                                                                       \
  } while (0)
#define RD_B(dst, slotoff)                                                  \
  do {                                                                      \
    const char* p_ = ldsb + 65536 + (slotoff) + thrB;                       \
    _Pragma("unroll") for (int n_ = 0; n_ < 2; ++n_) {                      \
      dst[n_][0] = *(const short8*)(p_ + x0 + n_ * 2048);                   \
      dst[n_][1] = *(const short8*)(p_ + x1 + n_ * 2048);                   \
    }                                                                       \
  } while (0)
#define MFQ(q, am, bn)                                                      \
  do {                                                                      \
    __builtin_amdgcn_s_setprio(1);                                          \
    _Pragma("unroll") for (int m_ = 0; m_ < 4; ++m_)                        \
        _Pragma("unroll") for (int n_ = 0; n_ < 2; ++n_)                    \
            _Pragma("unroll") for (int k_ = 0; k_ < 2; ++k_)                \
                acc[q][m_ * 2 + n_] = __builtin_amdgcn_mfma_f32_16x16x32_bf16( \
                    am[m_][k_], bn[n_][k_], acc[q][m_ * 2 + n_], 0, 0, 0);  \
    __builtin_amdgcn_s_setprio(0);                                          \
  } while (0)
#define VM(n) asm volatile("s_waitcnt vmcnt(" #n ")" ::: "memory")
#define BAR() __builtin_amdgcn_s_barrier()
#define CLOB() asm volatile("" ::: "memory")

  f32x4 zero = {0.f, 0.f, 0.f, 0.f};
  f32x4 acc[4][8];
#pragma unroll
  for (int q = 0; q < 4; ++q)
#pragma unroll
    for (int f = 0; f < 8; ++f) acc[q][f] = zero;

  // prologue: tile 0 halves in order [A0,B0,B1,A1]; then (EPI2) s_sc; pre-read aA,b0.
  stageA(0, 0); stageB(0, 0); stageB(1, 0); stageA(1, 0);
  if constexpr (EPI == 2) {
    for (int i = tid; i < 1024; i += 512) s_sc[i] = sc[m0 * 4 + i];
  }
  VM(4); BAR(); CLOB();
  RD_A(aA, 0);
  RD_B(b0, 0);

  for (int t = 0; t < NKT - 1; ++t) {
    int aS = (t & 1) * 32768;
    int bS = aS;                               // B offsets are +65536 inside RD_B
    int aS2 = aS ^ 32768;
    // p0: compute q0(A0,B0); read B1[t]; stage A0[t+1]
    stageA(0, t + 1);
    VM(4); BAR(); CLOB();
    RD_B(b1, bS + 16384);
    MFQ(0, aA, b0);
    // p1: compute q1(A0,B1); read A1[t]; stage B0[t+1]
    stageB(0, t + 1);
    VM(4); BAR(); CLOB();
    RD_A(aB, aS + 16384);
    MFQ(1, aA, b1);
    // p2: compute q2(A1,B0); read A0[t+1]; stage B1[t+1]
    stageB(1, t + 1);
    VM(4); BAR(); CLOB();
    RD_A(aA, aS2);
    MFQ(2, aB, b0);
    // p3: compute q3(A1,B1); read B0[t+1]; stage A1[t+1]
    stageA(1, t + 1);
    VM(4); BAR(); CLOB();
    RD_B(b0, aS2);
    MFQ(3, aB, b1);
  }
  {  // tail tile: no stages, drain progressively
    constexpr int t = NKT - 1;
    int aS = (t & 1) * 32768;
    VM(2); BAR(); CLOB();
    RD_B(b1, aS + 16384);
    MFQ(0, aA, b0);
    VM(0); BAR(); CLOB();
    RD_A(aB, aS + 16384);
    MFQ(1, aA, b1);
    MFQ(2, aB, b0);
    MFQ(3, aB, b1);
  }
#undef RD_A
#undef RD_B
#undef MFQ
#undef VM
#undef BAR
#undef CLOB

  if constexpr (EPI == 0) {
#pragma unroll
    for (int qm = 0; qm < 2; ++qm)
#pragma unroll
      for (int qn = 0; qn < 2; ++qn) {
        int q = qm * 2 + qn;
#pragma unroll
        for (int n = 0; n < 2; ++n) {
          int col = nt0 * 256 + qn * 128 + wn * 32 + n * 16 + (l & 15);
          float bb = bias[col];
#pragma unroll
          for (int m = 0; m < 4; ++m) {
            long rowb = m0 + qm * 128 + wm * 64 + m * 16 + ((l >> 4) << 2);
#pragma unroll
            for (int r = 0; r < 4; ++r)
              outb[(rowb + r) * 512 + col] = f2b(acc[q][m * 2 + n][r] + bb);
          }
        }
      }
  } else if constexpr (EPI == 1) {
    float part[2][2][4][4];
#pragma unroll
    for (int qm = 0; qm < 2; ++qm)
#pragma unroll
      for (int qn = 0; qn < 2; ++qn)
#pragma unroll
        for (int m = 0; m < 4; ++m)
#pragma unroll
          for (int r = 0; r < 4; ++r) part[qm][qn][m][r] = 0.f;
#pragma unroll
    for (int qm = 0; qm < 2; ++qm)
#pragma unroll
      for (int qn = 0; qn < 2; ++qn) {
        int q = qm * 2 + qn;
#pragma unroll
        for (int n = 0; n < 2; ++n) {
          int col = nt0 * 256 + qn * 128 + wn * 32 + n * 16 + (l & 15);
          float bb = bias[col];
#pragma unroll
          for (int m = 0; m < 4; ++m) {
            long rowb = m0 + qm * 128 + wm * 64 + m * 16 + ((l >> 4) << 2);
#pragma unroll
            for (int r = 0; r < 4; ++r) {
              float kv = acc[q][m * 2 + n][r] + bb;
              part[qm][qn][m][r] += kv * b2f(Qb[(rowb + r) * 512 + col]);
            }
          }
        }
      }
    __syncthreads();
    float (*sred)[2][4] = (float(*)[2][4])ldsb;   // [256][head2][wn4] = 8KB
#pragma unroll
    for (int qm = 0; qm < 2; ++qm)
#pragma unroll
      for (int qn = 0; qn < 2; ++qn)
#pragma unroll
        for (int m = 0; m < 4; ++m)
#pragma unroll
          for (int r = 0; r < 4; ++r) {
            float s = part[qm][qn][m][r];
            s += __shfl_xor(s, 1);
            s += __shfl_xor(s, 2);
            s += __shfl_xor(s, 4);
            s += __shfl_xor(s, 8);
            if ((l & 15) == 0)
              sred[qm * 128 + wm * 64 + m * 16 + ((l >> 4) << 2) + r][qn][wn] = s;
          }
    __syncthreads();
    {
      int row = tid >> 1, hh = tid & 1;
      float v = sred[row][hh][0] + sred[row][hh][1] + sred[row][hh][2] +
                sred[row][hh][3];
      sc[(m0 + row) * 4 + nt0 * 2 + hh] = v;
    }
  } else {
    __syncthreads();
    float* Zs = (float*)ldsb;                   // 256 x 64 f32 = 64 KB
#pragma unroll
    for (int qm = 0; qm < 2; ++qm)
#pragma unroll
      for (int qn = 0; qn < 2; ++qn) {
        int q = qm * 2 + qn;
#pragma unroll
        for (int n = 0; n < 2; ++n) {
          int pl = qn * 128 + wn * 32 + n * 16 + (l & 15);   // permuted col p=4d+h
          int pg = nt0 * 256 + pl;
          int h = pl & 3;
          float bb = bias[(pg & 3) * 1024 + (pg >> 2)];
#pragma unroll
          for (int m = 0; m < 4; ++m) {
            int rl = qm * 128 + wm * 64 + m * 16 + ((l >> 4) << 2);
#pragma unroll
            for (int r = 0; r < 4; ++r) {
              float z = s_sc[(rl + r) * 4 + h] * (acc[q][m * 2 + n][r] + bb);
              z = fmaxf(z, __shfl_xor(z, 1));   // max over heads (adjacent p)
              z = fmaxf(z, __shfl_xor(z, 2));
              if ((l & 3) == 0) Zs[(rl + r) * 64 + (pl >> 2)] = z;
            }
          }
        }
      }
    __syncthreads();
#pragma unroll
    for (int it = 0; it < 8; ++it) {            // coalesced float4 stores
      int i = it * 512 + tid;
      int row = i >> 4, d4 = i & 15;
      f32x4 v = *(const f32x4*)&Zs[row * 64 + d4 * 4];
      *(f32x4*)&Z[(m0 + row) * 1024 + nt0 * 64 + d4 * 4] = v;
    }
  }
}

// ---------------- fallback (only if ws too small): fp32, correct but slow ----------------
__global__ __launch_bounds__(256) void naive_k(
    const float* __restrict__ Xd, const float* __restrict__ Xo,
    const float* __restrict__ Wq, const float* __restrict__ bq,
    const float* __restrict__ Wk, const float* __restrict__ bk,
    const float* __restrict__ Wv, const float* __restrict__ bv,
    float* __restrict__ Z) {
  int i = blockIdx.x, t = threadIdx.x;
  __shared__ float xd[1024], xo[512], s[4];
  for (int j = t; j < 1024; j += 256) xd[j] = Xd[(size_t)i * 1024 + j];
  for (int j = t; j < 512; j += 256) xo[j] = Xo[(size_t)i * 512 + j];
  if (t < 4) s[t] = 0.f;
  __syncthreads();
  for (int c = t; c < 512; c += 256) {
    float q = bq[c], k = bk[c];
    for (int j = 0; j < 512; ++j) q += xo[j] * Wq[(size_t)j * 512 + c];
    for (int j = 0; j < 1024; ++j) k += xd[j] * Wk[(size_t)j * 512 + c];
    atomicAdd(&s[c >> 7], q * k);
  }
  __syncthreads();
  for (int d = t; d < 1024; d += 256) {
    float z = -INFINITY;
    for (int h = 0; h < 4; ++h) {
      float v = bv[h * 1024 + d];
      for (int j = 0; j < 1024; ++j) v += xd[j] * Wv[(size_t)j * 4096 + h * 1024 + d];
      z = fmaxf(z, s[h] * v);
    }
    Z[(size_t)i * 1024 + d] = z;
  }
}

extern "C" void kernel_launch(void* const* d_in, const int* in_sizes, int n_in,
                              void* d_out, int out_size, void* d_ws, size_t ws_size,
                              hipStream_t stream) {
  const float* Xd = (const float*)d_in[0];
  const float* Xo = (const float*)d_in[1];
  const float* Wq = (const float*)d_in[2];
  const float* bq = (const float*)d_in[3];
  const float* Wk = (const float*)d_in[4];
  const float* bk = (const float*)d_in[5];
  const float* Wv = (const float*)d_in[6];
  const float* bv = (const float*)d_in[7];
  float* Z = (float*)d_out;
  long N = in_sizes[0] / 1024;

  size_t sz_Xd = (size_t)N * 1024 * 2, sz_Xo = (size_t)N * 512 * 2;
  size_t sz_Wq = (size_t)512 * 512 * 2, sz_Wk = (size_t)512 * 1024 * 2;
  size_t sz_Wv = (size_t)4096 * 1024 * 2;
  size_t sz_Qb = (size_t)N * 512 * 2, sz_sc = (size_t)N * 4 * 4;
  size_t o_Xo = sz_Xd, o_Wq = o_Xo + sz_Xo, o_Wk = o_Wq + sz_Wq,
         o_Wv = o_Wk + sz_Wk, o_Qb = o_Wv + sz_Wv, o_sc = o_Qb + sz_Qb;
  size_t need = o_sc + sz_sc;

  if (ws_size < need || (N % 256) != 0) {
    naive_k<<<(int)N, 256, 0, stream>>>(Xd, Xo, Wq, bq, Wk, bk, Wv, bv, Z);
    return;
  }

  char* w = (char*)d_ws;
  unsigned short* Xd_b = (unsigned short*)w;
  unsigned short* Xo_b = (unsigned short*)(w + o_Xo);
  unsigned short* Wq_t = (unsigned short*)(w + o_Wq);
  unsigned short* Wk_t = (unsigned short*)(w + o_Wk);
  unsigned short* Wv_p = (unsigned short*)(w + o_Wv);
  unsigned short* Qb   = (unsigned short*)(w + o_Qb);
  float* sc = (float*)(w + o_sc);

  conv_k<<<2048, 256, 0, stream>>>(Xd, (short8*)Xd_b, N * 1024 / 8);
  conv_k<<<2048, 256, 0, stream>>>(Xo, (short8*)Xo_b, N * 512 / 8);
  tconv_k<<<dim3(16, 16), 256, 0, stream>>>(Wq, Wq_t, 512, 512, 0);
  tconv_k<<<dim3(32, 16), 256, 0, stream>>>(Wk, Wk_t, 1024, 512, 0);
  tconv_k<<<dim3(32, 128), 256, 0, stream>>>(Wv, Wv_p, 1024, 4096, 1);

  int mt = (int)(N / 256);
  gemm_p<512, 2, 0><<<mt * 2, 512, 0, stream>>>(Xo_b, Wq_t, bq, nullptr, Qb,
                                                nullptr, nullptr);
  gemm_p<1024, 2, 1><<<mt * 2, 512, 0, stream>>>(Xd_b, Wk_t, bk, Qb, nullptr,
                                                 sc, nullptr);
  gemm_p<1024, 16, 2><<<mt * 16, 512, 0, stream>>>(Xd_b, Wv_p, bv, nullptr,
                                                   nullptr, sc, Z);
}